// Round 1
// baseline (351.113 us; speedup 1.0000x reference)
//
#include <hip/hip_runtime.h>
#include <hip/hip_bf16.h>
#include <cstddef>

// OutputAttention: context = softmax_s(tanh(passage@W1 + hidden@W2)@Vw) . passage
// B=32, S=2048, D=512, U=512. All inputs fp32; outputs fp32.
// d_out = context[32*512] ++ attn[32*2048]. attn region doubles as score scratch.
// ws: W1p bf16-swizzled (512KB) + hproj (64KB) = 576KB needed.

#define NB 32
#define NS 2048
#define ND 512
#define NU 512

typedef __bf16 bf16_t;
typedef __bf16 bf16x8 __attribute__((ext_vector_type(8)));
typedef float floatx4 __attribute__((ext_vector_type(4)));

// ---------------------------------------------------------------------------
// K0: W1 [k=512][n=512] fp32 -> bf16, swizzled into MFMA-B fragment order.
// For 16x16x32 MFMA, lane L=q*16+c needs B[k0+q*8+jj][n0+c], jj=0..7.
// Layout: block (kc,ng) of 1KB; element (k,n) -> offset q*128 + c*8 + jj
// so lane L reads flat [block*512 + L*8] -> one coalesced 1KB dwordx4 burst.
__global__ void prep_w1(const float* __restrict__ W1, bf16_t* __restrict__ W1p) {
    int idx = blockIdx.x * 256 + threadIdx.x;     // 0..262143 = k*512+n
    int k = idx >> 9, n = idx & 511;
    int kc = k >> 5, q = (k >> 3) & 3, jj = k & 7;
    int ng = n >> 4, c = n & 15;
    int dst = (((kc << 5) + ng) << 9) + (q << 7) + (c << 3) + jj;
    W1p[dst] = (bf16_t)W1[idx];
}

// ---------------------------------------------------------------------------
// K1: hproj[b][u] = sum_d hidden[b][d] * W2[d][u]   (fp32, tiny)
__global__ __launch_bounds__(512) void hproj_kernel(
    const float* __restrict__ hidden, const float* __restrict__ W2,
    float* __restrict__ hproj) {
    __shared__ float h[ND];
    int b = blockIdx.x, u = threadIdx.x;
    h[u] = hidden[b * ND + u];
    __syncthreads();
    float acc = 0.f;
#pragma unroll 8
    for (int d = 0; d < ND; ++d) acc = fmaf(h[d], W2[d * NU + u], acc);
    hproj[b * NU + u] = acc;
}

// ---------------------------------------------------------------------------
// K2: scores[m] = sum_n tanh( (passage@W1)[m][n] + hproj[b][n] ) * Vw[n]
// 64 rows/block, full K=512 A-tile in 64KB LDS (bf16, XOR-swizzled 16B chunks
// to break the 1024B-stride bank conflict). 4 waves x (64 rows x 128 cols),
// B-frags streamed straight from L2 (pre-swizzled W1p) -> no k-loop barriers.
__global__ __launch_bounds__(256, 2) void score_kernel(
    const float* __restrict__ passage, const bf16_t* __restrict__ W1p,
    const float* __restrict__ hproj, const float* __restrict__ Vw,
    const float* __restrict__ Vb, float* __restrict__ scores) {
    __shared__ bf16_t Asf[64 * 512];              // 64KB exactly
    const int tid = threadIdx.x;
    const int wave = tid >> 6, lane = tid & 63;
    const int q = lane >> 4, c = lane & 15;
    const int m0 = blockIdx.x * 64;
    const int b = m0 >> 11;                       // 2048 rows per batch

    // Stage A: 64 rows x 512 k, fp32 -> bf16. Each wave fills one row per iter
    // (contiguous 1KB), chunk index XOR (row&7) for bank-conflict-free reads.
#pragma unroll
    for (int it = 0; it < 16; ++it) {
        int idx = it * 256 + tid;
        int row = idx >> 6, c8 = idx & 63;        // c8 = 8-float chunk in row
        const float4* src = (const float4*)(passage + ((size_t)(m0 + row) << 9)) + (c8 << 1);
        float4 v0 = src[0], v1 = src[1];
        bf16x8 w;
        w[0] = (bf16_t)v0.x; w[1] = (bf16_t)v0.y; w[2] = (bf16_t)v0.z; w[3] = (bf16_t)v0.w;
        w[4] = (bf16_t)v1.x; w[5] = (bf16_t)v1.y; w[6] = (bf16_t)v1.z; w[7] = (bf16_t)v1.w;
        ((bf16x8*)(Asf + (row << 9)))[c8 ^ (row & 7)] = w;
    }
    __syncthreads();

    floatx4 acc[4][8];
#pragma unroll
    for (int i = 0; i < 4; ++i)
#pragma unroll
        for (int j = 0; j < 8; ++j) { floatx4 z = {0.f, 0.f, 0.f, 0.f}; acc[i][j] = z; }

    // Barrier-free K loop: A frags from LDS, B frags coalesced from L2.
    for (int kc = 0; kc < 16; ++kc) {
        bf16x8 a[4];
        int chunk = (kc << 2) + q;                // (k0>>3)+q
#pragma unroll
        for (int i = 0; i < 4; ++i)
            a[i] = ((const bf16x8*)(Asf + ((i * 16 + c) << 9)))[chunk ^ (c & 7)];
#pragma unroll
        for (int j = 0; j < 8; ++j) {
            int ng = (wave << 3) + j;
            bf16x8 bb = ((const bf16x8*)(W1p + (((kc << 5) + ng) << 9)))[lane];
#pragma unroll
            for (int i = 0; i < 4; ++i)
                acc[i][j] = __builtin_amdgcn_mfma_f32_16x16x32_bf16(a[i], bb, acc[i][j], 0, 0, 0);
        }
    }

    // Epilogue: t = tanh(x) = 1 - 2/(1+e^{2x}); row-partials in sp[i][r].
    // C/D layout: col = c, row = i*16 + q*4 + r.
    float sp[4][4];
#pragma unroll
    for (int i = 0; i < 4; ++i)
#pragma unroll
        for (int r = 0; r < 4; ++r) sp[i][r] = 0.f;
#pragma unroll
    for (int j = 0; j < 8; ++j) {
        int n = (wave << 7) + (j << 4) + c;
        float hp = hproj[(b << 9) + n];
        float vw = Vw[n];
#pragma unroll
        for (int i = 0; i < 4; ++i)
#pragma unroll
            for (int r = 0; r < 4; ++r) {
                float x = acc[i][j][r] + hp;
                float e = __expf(2.0f * x);                    // inf ok
                float t = 1.0f - 2.0f * __builtin_amdgcn_rcpf(e + 1.0f);
                sp[i][r] = fmaf(t, vw, sp[i][r]);
            }
    }
    // Reduce over the 16 column-lanes (low 4 lane bits).
#pragma unroll
    for (int off = 1; off < 16; off <<= 1)
#pragma unroll
        for (int i = 0; i < 4; ++i)
#pragma unroll
            for (int r = 0; r < 4; ++r)
                sp[i][r] += __shfl_xor(sp[i][r], off, 64);

    __syncthreads();                               // done reading Asf -> reuse
    float* red = (float*)Asf;                      // [4 waves][64 rows]
    if (c == 0) {
#pragma unroll
        for (int i = 0; i < 4; ++i)
#pragma unroll
            for (int r = 0; r < 4; ++r)
                red[wave * 64 + i * 16 + q * 4 + r] = sp[i][r];
    }
    __syncthreads();
    if (tid < 64)
        scores[m0 + tid] = red[tid] + red[64 + tid] + red[128 + tid] + red[192 + tid] + Vb[0];
}

// ---------------------------------------------------------------------------
// K3: masked softmax over S, in place on the attn region of d_out.
__global__ __launch_bounds__(256) void softmax_kernel(
    const float* __restrict__ mask, float* __restrict__ attn) {
    __shared__ float sm[256];
    int b = blockIdx.x, tid = threadIdx.x;
    const int base = b * NS;
    float v[8];
    float mx = -1e38f;
#pragma unroll
    for (int i = 0; i < 8; ++i) {
        int s = i * 256 + tid;
        float sc = attn[base + s] + (1.0f - mask[base + s]) * (-1e30f);
        v[i] = sc;
        mx = fmaxf(mx, sc);
    }
    sm[tid] = mx; __syncthreads();
    for (int off = 128; off > 0; off >>= 1) {
        if (tid < off) sm[tid] = fmaxf(sm[tid], sm[tid + off]);
        __syncthreads();
    }
    mx = sm[0]; __syncthreads();
    float sum = 0.f;
#pragma unroll
    for (int i = 0; i < 8; ++i) { v[i] = __expf(v[i] - mx); sum += v[i]; }
    sm[tid] = sum; __syncthreads();
    for (int off = 128; off > 0; off >>= 1) {
        if (tid < off) sm[tid] += sm[tid + off];
        __syncthreads();
    }
    float inv = 1.0f / sm[0];
#pragma unroll
    for (int i = 0; i < 8; ++i) attn[base + i * 256 + tid] = v[i] * inv;
}

// ---------------------------------------------------------------------------
// K4: context[b][d] = sum_s attn[b][s] * passage[b][s][d]. 2nd pass over
// passage at HBM rate; 64-s chunks per block, fp32 atomics into zeroed ctx.
__global__ __launch_bounds__(128) void context_kernel(
    const float* __restrict__ passage, const float* __restrict__ attn,
    float* __restrict__ ctx) {
    int b = blockIdx.x >> 5, sc = blockIdx.x & 31, t = threadIdx.x;
    const float4* p = (const float4*)(passage + (((size_t)b * NS + sc * 64) << 9));
    const float* wp = attn + b * NS + sc * 64;
    float ax = 0.f, ay = 0.f, az = 0.f, aw = 0.f;
#pragma unroll 4
    for (int s = 0; s < 64; ++s) {
        float w = wp[s];
        float4 v = p[(size_t)s * 128 + t];
        ax = fmaf(w, v.x, ax); ay = fmaf(w, v.y, ay);
        az = fmaf(w, v.z, az); aw = fmaf(w, v.w, aw);
    }
    float* dst = ctx + b * ND + t * 4;
    atomicAdd(dst + 0, ax); atomicAdd(dst + 1, ay);
    atomicAdd(dst + 2, az); atomicAdd(dst + 3, aw);
}

// ---------------------------------------------------------------------------
extern "C" void kernel_launch(void* const* d_in, const int* in_sizes, int n_in,
                              void* d_out, int out_size, void* d_ws, size_t ws_size,
                              hipStream_t stream) {
    const float* passage = (const float*)d_in[0];   // [32,2048,512]
    const float* hidden  = (const float*)d_in[1];   // [32,512]
    const float* mask    = (const float*)d_in[2];   // [32,2048]
    const float* W1      = (const float*)d_in[3];   // [512,512]
    const float* W2      = (const float*)d_in[4];   // [512,512]
    const float* Vw      = (const float*)d_in[5];   // [512]
    const float* Vb      = (const float*)d_in[6];   // [1]

    float* ctx  = (float*)d_out;                    // [32*512]
    float* attn = (float*)d_out + NB * ND;          // [32*2048] (scores scratch too)

    bf16_t* W1p  = (bf16_t*)d_ws;                               // 512KB
    float* hproj = (float*)((char*)d_ws + (size_t)NU * ND * 2); // 64KB

    hipMemsetAsync(ctx, 0, (size_t)NB * ND * sizeof(float), stream);
    prep_w1<<<dim3(1024), dim3(256), 0, stream>>>(W1, W1p);
    hproj_kernel<<<dim3(NB), dim3(512), 0, stream>>>(hidden, W2, hproj);
    score_kernel<<<dim3(NB * NS / 64), dim3(256), 0, stream>>>(passage, W1p, hproj, Vw, Vb, attn);
    softmax_kernel<<<dim3(NB), dim3(256), 0, stream>>>(mask, attn);
    context_kernel<<<dim3(NB * 32), dim3(128), 0, stream>>>(passage, attn, ctx);
}

// Round 2
// 292.013 us; speedup vs baseline: 1.2024x; 1.2024x over previous
//
#include <hip/hip_runtime.h>
#include <hip/hip_bf16.h>
#include <cstddef>

// OutputAttention: context = softmax_s(tanh(passage@W1 + hidden@W2)@Vw) . passage
// B=32, S=2048, D=512, U=512. All inputs fp32; outputs fp32.
// d_out = context[32*512] ++ attn[32*2048]. attn region doubles as score scratch.

#define NB 32
#define NS 2048
#define ND 512
#define NU 512

typedef __bf16 bf16_t;
typedef __bf16 bf16x8 __attribute__((ext_vector_type(8)));
typedef float floatx4 __attribute__((ext_vector_type(4)));

// ---------------------------------------------------------------------------
// K0 fused: blocks [0,1024): W1 fp32->bf16 swizzle into MFMA-B frag order.
//           blocks [1024,1152): hproj[b][u] = sum_d hidden[b][d]*W2[d][u].
// B-frag layout: block (kc,ng) of 512 elems; lane L reads flat [blk*512+L*8]
// -> one coalesced 1KB dwordx4 burst per frag.
__global__ __launch_bounds__(256) void prep_kernel(
    const float* __restrict__ W1, bf16_t* __restrict__ W1p,
    const float* __restrict__ hidden, const float* __restrict__ W2,
    float* __restrict__ hproj) {
    if (blockIdx.x < 1024) {
        int idx = blockIdx.x * 256 + threadIdx.x;     // k*512+n
        int k = idx >> 9, n = idx & 511;
        int kc = k >> 5, q = (k >> 3) & 3, jj = k & 7;
        int ng = n >> 4, c = n & 15;
        int dst = (((kc << 5) + ng) << 9) + (q << 7) + (c << 3) + jj;
        W1p[dst] = (bf16_t)W1[idx];
    } else {
        __shared__ float h[ND];
        __shared__ float part[256];
        int bi = blockIdx.x - 1024;                   // 0..127
        int b = bi >> 2, ug = bi & 3;
        int t = threadIdx.x;
        h[t] = hidden[b * ND + t];
        h[t + 256] = hidden[b * ND + t + 256];
        __syncthreads();
        int u = (ug << 7) + (t & 127);
        int d0 = (t >> 7) << 8;                       // 0 or 256
        float acc = 0.f;
#pragma unroll 8
        for (int d = d0; d < d0 + 256; ++d) acc = fmaf(h[d], W2[d * NU + u], acc);
        part[t] = acc;
        __syncthreads();
        if (t < 128) hproj[b * NU + u] = part[t] + part[t + 128];
    }
}

// ---------------------------------------------------------------------------
// K2: scores[m] = sum_n tanh((passage@W1)[m][n] + hproj[b][n]) * Vw[n] + Vb
// 64 rows/block, K=512 A-tile in 64KB LDS (bf16, XOR-swizzled). 4 waves x
// (64 rows x 128 cols). Barrier-free k-loop; A-frags + B-frags explicitly
// double-buffered in registers (ping-pong, 2x unroll) so the 12 loads of
// step k+1 overlap the 32 MFMAs of step k.
__global__ __launch_bounds__(256, 2) void score_kernel(
    const float* __restrict__ passage, const bf16_t* __restrict__ W1p,
    const float* __restrict__ hproj, const float* __restrict__ Vw,
    const float* __restrict__ Vb, float* __restrict__ scores) {
    __shared__ bf16_t Asf[64 * 512];              // 64KB
    const int tid = threadIdx.x;
    const int wave = tid >> 6, lane = tid & 63;
    const int q = lane >> 4, c = lane & 15;
    const int m0 = blockIdx.x * 64;
    const int b = m0 >> 11;

    // Stage A: 64 rows x 512 k, fp32 -> bf16, chunk XOR (row&7) swizzle.
#pragma unroll
    for (int it = 0; it < 16; ++it) {
        int idx = it * 256 + tid;
        int row = idx >> 6, c8 = idx & 63;
        const float4* src = (const float4*)(passage + ((size_t)(m0 + row) << 9)) + (c8 << 1);
        float4 v0 = src[0], v1 = src[1];
        bf16x8 w;
        w[0] = (bf16_t)v0.x; w[1] = (bf16_t)v0.y; w[2] = (bf16_t)v0.z; w[3] = (bf16_t)v0.w;
        w[4] = (bf16_t)v1.x; w[5] = (bf16_t)v1.y; w[6] = (bf16_t)v1.z; w[7] = (bf16_t)v1.w;
        ((bf16x8*)(Asf + (row << 9)))[c8 ^ (row & 7)] = w;
    }
    __syncthreads();

    floatx4 acc[4][8];
#pragma unroll
    for (int i = 0; i < 4; ++i)
#pragma unroll
        for (int j = 0; j < 8; ++j) { floatx4 z = {0.f, 0.f, 0.f, 0.f}; acc[i][j] = z; }

    const bf16x8* Wq = (const bf16x8*)W1p;         // 64 frag-chunks per (kc,ng) block
    const int wj0 = wave << 3;

#define LOAD_A(dst, kc_) {                                                   \
    int chunk = ((kc_) << 2) + q;                                            \
    _Pragma("unroll")                                                        \
    for (int i = 0; i < 4; ++i)                                              \
        dst[i] = ((const bf16x8*)(Asf + ((i * 16 + c) << 9)))[chunk ^ (c & 7)]; }
#define LOAD_B(dst, kc_) {                                                   \
    _Pragma("unroll")                                                        \
    for (int j = 0; j < 8; ++j)                                              \
        dst[j] = Wq[((((kc_) << 5) + wj0 + j) << 6) + lane]; }
#define MFMA_GRP(a_, b_) {                                                   \
    _Pragma("unroll")                                                        \
    for (int j = 0; j < 8; ++j)                                              \
        _Pragma("unroll")                                                    \
        for (int i = 0; i < 4; ++i)                                          \
            acc[i][j] = __builtin_amdgcn_mfma_f32_16x16x32_bf16(a_[i], b_[j], acc[i][j], 0, 0, 0); }

    bf16x8 a0[4], a1[4], b0[8], b1[8];
    LOAD_A(a0, 0); LOAD_B(b0, 0);
    for (int kc = 0; kc < 16; kc += 2) {
        LOAD_A(a1, kc + 1); LOAD_B(b1, kc + 1);
        MFMA_GRP(a0, b0);
        int kn = (kc + 2) & 15;                    // kc=14 wraps to 0 (dead load)
        LOAD_A(a0, kn); LOAD_B(b0, kn);
        MFMA_GRP(a1, b1);
    }
#undef LOAD_A
#undef LOAD_B
#undef MFMA_GRP

    // Epilogue: tanh(x) = 1 - 2/(1+e^{2x}); C/D layout col=c, row=i*16+q*4+r.
    float sp[4][4];
#pragma unroll
    for (int i = 0; i < 4; ++i)
#pragma unroll
        for (int r = 0; r < 4; ++r) sp[i][r] = 0.f;
#pragma unroll
    for (int j = 0; j < 8; ++j) {
        int n = (wave << 7) + (j << 4) + c;
        float hp = hproj[(b << 9) + n];
        float vw = Vw[n];
#pragma unroll
        for (int i = 0; i < 4; ++i)
#pragma unroll
            for (int r = 0; r < 4; ++r) {
                float x = acc[i][j][r] + hp;
                float e = __expf(2.0f * x);
                float t = 1.0f - 2.0f * __builtin_amdgcn_rcpf(e + 1.0f);
                sp[i][r] = fmaf(t, vw, sp[i][r]);
            }
    }
#pragma unroll
    for (int off = 1; off < 16; off <<= 1)
#pragma unroll
        for (int i = 0; i < 4; ++i)
#pragma unroll
            for (int r = 0; r < 4; ++r)
                sp[i][r] += __shfl_xor(sp[i][r], off, 64);

    __syncthreads();                               // all waves done with Asf
    float* red = (float*)Asf;
    if (c == 0) {
#pragma unroll
        for (int i = 0; i < 4; ++i)
#pragma unroll
            for (int r = 0; r < 4; ++r)
                red[wave * 64 + i * 16 + q * 4 + r] = sp[i][r];
    }
    __syncthreads();
    if (tid < 64)
        scores[m0 + tid] = red[tid] + red[64 + tid] + red[128 + tid] + red[192 + tid] + Vb[0];
}

// ---------------------------------------------------------------------------
// K3: masked softmax over S, in place on the attn region of d_out.
__global__ __launch_bounds__(256) void softmax_kernel(
    const float* __restrict__ mask, float* __restrict__ attn) {
    __shared__ float sm[256];
    int b = blockIdx.x, tid = threadIdx.x;
    const int base = b * NS;
    float v[8];
    float mx = -1e38f;
#pragma unroll
    for (int i = 0; i < 8; ++i) {
        int s = i * 256 + tid;
        float sc = attn[base + s] + (1.0f - mask[base + s]) * (-1e30f);
        v[i] = sc;
        mx = fmaxf(mx, sc);
    }
    sm[tid] = mx; __syncthreads();
    for (int off = 128; off > 0; off >>= 1) {
        if (tid < off) sm[tid] = fmaxf(sm[tid], sm[tid + off]);
        __syncthreads();
    }
    mx = sm[0]; __syncthreads();
    float sum = 0.f;
#pragma unroll
    for (int i = 0; i < 8; ++i) { v[i] = __expf(v[i] - mx); sum += v[i]; }
    sm[tid] = sum; __syncthreads();
    for (int off = 128; off > 0; off >>= 1) {
        if (tid < off) sm[tid] += sm[tid + off];
        __syncthreads();
    }
    float inv = 1.0f / sm[0];
#pragma unroll
    for (int i = 0; i < 8; ++i) attn[base + i * 256 + tid] = v[i] * inv;
}

// ---------------------------------------------------------------------------
// K4: context[b][d] = sum_s attn[b][s] * passage[b][s][d].
__global__ __launch_bounds__(128) void context_kernel(
    const float* __restrict__ passage, const float* __restrict__ attn,
    float* __restrict__ ctx) {
    int b = blockIdx.x >> 5, sc = blockIdx.x & 31, t = threadIdx.x;
    const float4* p = (const float4*)(passage + (((size_t)b * NS + sc * 64) << 9));
    const float* wp = attn + b * NS + sc * 64;
    float ax = 0.f, ay = 0.f, az = 0.f, aw = 0.f;
#pragma unroll 8
    for (int s = 0; s < 64; ++s) {
        float w = wp[s];
        float4 v = p[(size_t)s * 128 + t];
        ax = fmaf(w, v.x, ax); ay = fmaf(w, v.y, ay);
        az = fmaf(w, v.z, az); aw = fmaf(w, v.w, aw);
    }
    float* dst = ctx + b * ND + t * 4;
    atomicAdd(dst + 0, ax); atomicAdd(dst + 1, ay);
    atomicAdd(dst + 2, az); atomicAdd(dst + 3, aw);
}

// ---------------------------------------------------------------------------
extern "C" void kernel_launch(void* const* d_in, const int* in_sizes, int n_in,
                              void* d_out, int out_size, void* d_ws, size_t ws_size,
                              hipStream_t stream) {
    const float* passage = (const float*)d_in[0];
    const float* hidden  = (const float*)d_in[1];
    const float* mask    = (const float*)d_in[2];
    const float* W1      = (const float*)d_in[3];
    const float* W2      = (const float*)d_in[4];
    const float* Vw      = (const float*)d_in[5];
    const float* Vb      = (const float*)d_in[6];

    float* ctx  = (float*)d_out;                    // [32*512]
    float* attn = (float*)d_out + NB * ND;          // [32*2048] (score scratch)

    bf16_t* W1p  = (bf16_t*)d_ws;                               // 512KB
    float* hproj = (float*)((char*)d_ws + (size_t)NU * ND * 2); // 64KB

    hipMemsetAsync(ctx, 0, (size_t)NB * ND * sizeof(float), stream);
    prep_kernel<<<dim3(1024 + 128), dim3(256), 0, stream>>>(W1, W1p, hidden, W2, hproj);
    score_kernel<<<dim3(NB * NS / 64), dim3(256), 0, stream>>>(passage, W1p, hproj, Vw, Vb, attn);
    softmax_kernel<<<dim3(NB), dim3(256), 0, stream>>>(mask, attn);
    context_kernel<<<dim3(NB * 32), dim3(128), 0, stream>>>(passage, attn, ctx);
}

// Round 3
// 271.994 us; speedup vs baseline: 1.2909x; 1.0736x over previous
//
#include <hip/hip_runtime.h>
#include <hip/hip_bf16.h>
#include <cstddef>

// OutputAttention: context = softmax_s(tanh(passage@W1 + hidden@W2)@Vw) . passage
// B=32, S=2048, D=512, U=512. All inputs fp32; outputs fp32.
// d_out = context[32*512] ++ attn[32*2048]. attn region doubles as score scratch.

#define NB 32
#define NS 2048
#define ND 512
#define NU 512

typedef __bf16 bf16_t;
typedef __bf16 bf16x8 __attribute__((ext_vector_type(8)));
typedef float floatx4 __attribute__((ext_vector_type(4)));

// ---------------------------------------------------------------------------
// K0 fused: blocks [0,1024): W1 fp32->bf16 swizzle into MFMA-B frag order.
//           blocks [1024,1152): hproj[b][u] = sum_d hidden[b][d]*W2[d][u].
// B-frag layout: block (kc,ng) of 512 elems; lane L reads flat [blk*512+L*8]
// -> one coalesced 1KB dwordx4 burst per frag.
__global__ __launch_bounds__(256) void prep_kernel(
    const float* __restrict__ W1, bf16_t* __restrict__ W1p,
    const float* __restrict__ hidden, const float* __restrict__ W2,
    float* __restrict__ hproj) {
    if (blockIdx.x < 1024) {
        int idx = blockIdx.x * 256 + threadIdx.x;     // k*512+n
        int k = idx >> 9, n = idx & 511;
        int kc = k >> 5, q = (k >> 3) & 3, jj = k & 7;
        int ng = n >> 4, c = n & 15;
        int dst = (((kc << 5) + ng) << 9) + (q << 7) + (c << 3) + jj;
        W1p[dst] = (bf16_t)W1[idx];
    } else {
        __shared__ float h[ND];
        __shared__ float part[256];
        int bi = blockIdx.x - 1024;                   // 0..127
        int b = bi >> 2, ug = bi & 3;
        int t = threadIdx.x;
        h[t] = hidden[b * ND + t];
        h[t + 256] = hidden[b * ND + t + 256];
        __syncthreads();
        int u = (ug << 7) + (t & 127);
        int d0 = (t >> 7) << 8;                       // 0 or 256
        float acc = 0.f;
#pragma unroll 8
        for (int d = d0; d < d0 + 256; ++d) acc = fmaf(h[d], W2[d * NU + u], acc);
        part[t] = acc;
        __syncthreads();
        if (t < 128) hproj[b * NU + u] = part[t] + part[t + 128];
    }
}

// ---------------------------------------------------------------------------
// K2: scores[m] = sum_n tanh((passage@W1)[m][n] + hproj[b][n]) * Vw[n] + Vb
// 64 rows/block, K=512 A-tile in 64KB LDS (bf16, XOR-swizzled). 8 waves x
// (64 rows x 64 cols), acc[4][4]=64 AGPR; launch_bounds(512,4) caps the wave
// at 128 unified regs -> 4 waves/SIMD (16 waves/CU). TLP (not ILP) hides the
// L2 B-frag latency: per kc a wave issues 8 loads + 16 MFMAs; 4 resident
// waves keep the MFMA pipe fed. Barrier-free k-loop (A read-only in LDS,
// B streamed from L2 in pre-swizzled frag order).
__global__ __launch_bounds__(512, 4) void score_kernel(
    const float* __restrict__ passage, const bf16_t* __restrict__ W1p,
    const float* __restrict__ hproj, const float* __restrict__ Vw,
    const float* __restrict__ Vb, float* __restrict__ scores) {
    __shared__ bf16_t Asf[64 * 512];              // 64KB
    const int tid = threadIdx.x;
    const int wave = tid >> 6, lane = tid & 63;
    const int q = lane >> 4, c = lane & 15;
    const int m0 = blockIdx.x * 64;
    const int b = m0 >> 11;

    // Stage A: 64 rows x 512 k, fp32 -> bf16, chunk XOR (row&7) swizzle.
#pragma unroll
    for (int it = 0; it < 8; ++it) {
        int idx = it * 512 + tid;
        int row = idx >> 6, c8 = idx & 63;
        const float4* src = (const float4*)(passage + ((size_t)(m0 + row) << 9)) + (c8 << 1);
        float4 v0 = src[0], v1 = src[1];
        bf16x8 w;
        w[0] = (bf16_t)v0.x; w[1] = (bf16_t)v0.y; w[2] = (bf16_t)v0.z; w[3] = (bf16_t)v0.w;
        w[4] = (bf16_t)v1.x; w[5] = (bf16_t)v1.y; w[6] = (bf16_t)v1.z; w[7] = (bf16_t)v1.w;
        ((bf16x8*)(Asf + (row << 9)))[c8 ^ (row & 7)] = w;
    }
    __syncthreads();

    floatx4 acc[4][4];
#pragma unroll
    for (int i = 0; i < 4; ++i)
#pragma unroll
        for (int j = 0; j < 4; ++j) { floatx4 z = {0.f, 0.f, 0.f, 0.f}; acc[i][j] = z; }

    const bf16x8* Wq = (const bf16x8*)W1p;         // 64 frag-chunks per (kc,ng) block
    const int ng0 = wave << 2;

    for (int kc = 0; kc < 16; ++kc) {
        bf16x8 a[4], bb[4];
        int chunk = (kc << 2) + q;
#pragma unroll
        for (int i = 0; i < 4; ++i)
            a[i] = ((const bf16x8*)(Asf + ((i * 16 + c) << 9)))[chunk ^ (c & 7)];
#pragma unroll
        for (int j = 0; j < 4; ++j)
            bb[j] = Wq[(((kc << 5) + ng0 + j) << 6) + lane];
#pragma unroll
        for (int j = 0; j < 4; ++j)
#pragma unroll
            for (int i = 0; i < 4; ++i)
                acc[i][j] = __builtin_amdgcn_mfma_f32_16x16x32_bf16(a[i], bb[j], acc[i][j], 0, 0, 0);
    }

    // Epilogue: tanh(x) = 1 - 2/(1+e^{2x}); C/D layout col=c, row=i*16+q*4+r.
    float sp[4][4];
#pragma unroll
    for (int i = 0; i < 4; ++i)
#pragma unroll
        for (int r = 0; r < 4; ++r) sp[i][r] = 0.f;
#pragma unroll
    for (int j = 0; j < 4; ++j) {
        int n = (wave << 6) + (j << 4) + c;
        float hp = hproj[(b << 9) + n];
        float vw = Vw[n];
#pragma unroll
        for (int i = 0; i < 4; ++i)
#pragma unroll
            for (int r = 0; r < 4; ++r) {
                float x = acc[i][j][r] + hp;
                float e = __expf(2.0f * x);
                float t = 1.0f - 2.0f * __builtin_amdgcn_rcpf(e + 1.0f);
                sp[i][r] = fmaf(t, vw, sp[i][r]);
            }
    }
#pragma unroll
    for (int off = 1; off < 16; off <<= 1)
#pragma unroll
        for (int i = 0; i < 4; ++i)
#pragma unroll
            for (int r = 0; r < 4; ++r)
                sp[i][r] += __shfl_xor(sp[i][r], off, 64);

    __syncthreads();                               // all waves done with Asf
    float* red = (float*)Asf;                      // [8 waves][64 rows]
    if (c == 0) {
#pragma unroll
        for (int i = 0; i < 4; ++i)
#pragma unroll
            for (int r = 0; r < 4; ++r)
                red[wave * 64 + i * 16 + q * 4 + r] = sp[i][r];
    }
    __syncthreads();
    if (tid < 64) {
        float s = Vb[0];
#pragma unroll
        for (int w = 0; w < 8; ++w) s += red[w * 64 + tid];
        scores[m0 + tid] = s;
    }
}

// ---------------------------------------------------------------------------
// K3: masked softmax over S, in place on attn. 32 blocks x 1024 threads.
__global__ __launch_bounds__(1024) void softmax_kernel(
    const float* __restrict__ mask, float* __restrict__ attn) {
    __shared__ float smx[16], ssm[16];
    int b = blockIdx.x, tid = threadIdx.x;
    int wave = tid >> 6, lane = tid & 63;
    const int base = b * NS;
    float v0 = attn[base + tid] + (1.0f - mask[base + tid]) * (-1e30f);
    float v1 = attn[base + 1024 + tid] + (1.0f - mask[base + 1024 + tid]) * (-1e30f);
    float mx = fmaxf(v0, v1);
#pragma unroll
    for (int off = 1; off < 64; off <<= 1) mx = fmaxf(mx, __shfl_xor(mx, off, 64));
    if (lane == 0) smx[wave] = mx;
    __syncthreads();
    mx = smx[0];
#pragma unroll
    for (int w = 1; w < 16; ++w) mx = fmaxf(mx, smx[w]);
    v0 = __expf(v0 - mx); v1 = __expf(v1 - mx);
    float sum = v0 + v1;
#pragma unroll
    for (int off = 1; off < 64; off <<= 1) sum += __shfl_xor(sum, off, 64);
    if (lane == 0) ssm[wave] = sum;
    __syncthreads();
    sum = 0.f;
#pragma unroll
    for (int w = 0; w < 16; ++w) sum += ssm[w];
    float inv = 1.0f / sum;
    attn[base + tid] = v0 * inv;
    attn[base + 1024 + tid] = v1 * inv;
}

// ---------------------------------------------------------------------------
// K4: context[b][d] = sum_s attn[b][s] * passage[b][s][d]. 1024 blocks x 256
// threads: two 32-row halves accumulate in regs, LDS-combine, one atomic per
// (block, d4). 16 waves/CU streaming HBM.
__global__ __launch_bounds__(256) void context_kernel(
    const float* __restrict__ passage, const float* __restrict__ attn,
    float* __restrict__ ctx) {
    __shared__ float4 part[256];
    int bb = blockIdx.x >> 5, sc = blockIdx.x & 31, t = threadIdx.x;
    int col = t & 127, half = t >> 7;
    const float4* p = (const float4*)(passage + (((size_t)bb * NS + sc * 64 + half * 32) << 9));
    const float* wp = attn + bb * NS + sc * 64 + half * 32;
    float ax = 0.f, ay = 0.f, az = 0.f, aw = 0.f;
#pragma unroll 8
    for (int s = 0; s < 32; ++s) {
        float w = wp[s];
        float4 v = p[(size_t)s * 128 + col];
        ax = fmaf(w, v.x, ax); ay = fmaf(w, v.y, ay);
        az = fmaf(w, v.z, az); aw = fmaf(w, v.w, aw);
    }
    float4 mine; mine.x = ax; mine.y = ay; mine.z = az; mine.w = aw;
    part[t] = mine;
    __syncthreads();
    if (t < 128) {
        float4 o = part[t + 128];
        float* dst = ctx + bb * ND + t * 4;
        atomicAdd(dst + 0, ax + o.x); atomicAdd(dst + 1, ay + o.y);
        atomicAdd(dst + 2, az + o.z); atomicAdd(dst + 3, aw + o.w);
    }
}

// ---------------------------------------------------------------------------
extern "C" void kernel_launch(void* const* d_in, const int* in_sizes, int n_in,
                              void* d_out, int out_size, void* d_ws, size_t ws_size,
                              hipStream_t stream) {
    const float* passage = (const float*)d_in[0];
    const float* hidden  = (const float*)d_in[1];
    const float* mask    = (const float*)d_in[2];
    const float* W1      = (const float*)d_in[3];
    const float* W2      = (const float*)d_in[4];
    const float* Vw      = (const float*)d_in[5];
    const float* Vb      = (const float*)d_in[6];

    float* ctx  = (float*)d_out;                    // [32*512]
    float* attn = (float*)d_out + NB * ND;          // [32*2048] (score scratch)

    bf16_t* W1p  = (bf16_t*)d_ws;                               // 512KB
    float* hproj = (float*)((char*)d_ws + (size_t)NU * ND * 2); // 64KB

    hipMemsetAsync(ctx, 0, (size_t)NB * ND * sizeof(float), stream);
    prep_kernel<<<dim3(1024 + 128), dim3(256), 0, stream>>>(W1, W1p, hidden, W2, hproj);
    score_kernel<<<dim3(NB * NS / 64), dim3(512), 0, stream>>>(passage, W1p, hproj, Vw, Vb, attn);
    softmax_kernel<<<dim3(NB), dim3(1024), 0, stream>>>(mask, attn);
    context_kernel<<<dim3(NB * 32), dim3(256), 0, stream>>>(passage, attn, ctx);
}